// Round 5
// baseline (192.395 us; speedup 1.0000x reference)
//
#include <hip/hip_runtime.h>
#include <hip/hip_bf16.h>

#define NBINS 600
#define NCOPIES 32  // c = tid&31 -> lane's atomic ALWAYS hits bank c: zero bank conflicts

#define ATOM4(v)                                   \
    atomicAdd(&h[(v).x * NCOPIES + c], 1);         \
    atomicAdd(&h[(v).y * NCOPIES + c], 1);         \
    atomicAdd(&h[(v).z * NCOPIES + c], 1);         \
    atomicAdd(&h[(v).w * NCOPIES + c], 1);

// Kernel A: per-block 32-copy LDS histogram -> plain-store partials (idempotent).
__global__ __launch_bounds__(512) void bincount_part(
        const int* __restrict__ x, int n, int* __restrict__ part) {
    __shared__ int h[NBINS * NCOPIES];  // 76800 B -> 2 blocks/CU, 16 waves/CU

    for (int i = threadIdx.x; i < NBINS * NCOPIES; i += 512) h[i] = 0;
    __syncthreads();

    const int c = threadIdx.x & (NCOPIES - 1);
    const int n4 = n >> 2;
    const int4* __restrict__ x4 = (const int4*)x;
    const int nth = gridDim.x * 512;
    const int base = blockIdx.x * 512 + threadIdx.x;
    const int per = n4 / nth;

    if (per * nth == n4 && (per & 3) == 0) {
        // fast path (n4 divides evenly, per % 4 == 0): prefetch 4 int4 ahead
        int4 v0 = x4[base];
        int4 v1 = x4[base + nth];
        int4 v2 = x4[base + 2 * nth];
        int4 v3 = x4[base + 3 * nth];
        for (int k = 4; k < per; k += 4) {
            int4 p0 = x4[base + (k + 0) * nth];
            int4 p1 = x4[base + (k + 1) * nth];
            int4 p2 = x4[base + (k + 2) * nth];
            int4 p3 = x4[base + (k + 3) * nth];
            ATOM4(v0); ATOM4(v1); ATOM4(v2); ATOM4(v3);
            v0 = p0; v1 = p1; v2 = p2; v3 = p3;
        }
        ATOM4(v0); ATOM4(v1); ATOM4(v2); ATOM4(v3);
    } else {
        for (int i = base; i < n4; i += nth) {
            int4 v = x4[i];
            ATOM4(v);
        }
    }
    // scalar tail (n % 4), block 0 only
    if (blockIdx.x == 0) {
        for (int t = (n4 << 2) + (int)threadIdx.x; t < n; t += 512)
            atomicAdd(&h[x[t] * NCOPIES + c], 1);
    }

    __syncthreads();

    // per-block partial: rotate copy index by lane (avoid 64-way broadcast bank hit)
    for (int b = threadIdx.x; b < NBINS; b += 512) {
        int s = 0;
        #pragma unroll
        for (int j = 0; j < NCOPIES; ++j)
            s += h[b * NCOPIES + ((j + threadIdx.x) & (NCOPIES - 1))];
        part[blockIdx.x * NBINS + b] = s;  // plain store, coalesced
    }
}

// Kernel B: one wave per bin; shuffle-reduce over block partials; plain store.
__global__ __launch_bounds__(64) void bincount_reduce(
        const int* __restrict__ part, int nblocks, int* __restrict__ out) {
    const int bin = blockIdx.x;
    const int t = threadIdx.x;
    int s = 0;
    for (int b = t; b < nblocks; b += 64)
        s += part[b * NBINS + bin];
    #pragma unroll
    for (int off = 32; off > 0; off >>= 1)
        s += __shfl_down(s, off, 64);
    if (t == 0) out[bin] = s;
}

extern "C" void kernel_launch(void* const* d_in, const int* in_sizes, int n_in,
                              void* d_out, int out_size, void* d_ws, size_t ws_size,
                              hipStream_t stream) {
    const int* x = (const int*)d_in[0];
    int* out = (int*)d_out;
    int* part = (int*)d_ws;
    const int n = in_sizes[0];

    int nblocks = 512;  // 2 blocks/CU on 256 CUs, all resident
    while ((size_t)nblocks * NBINS * sizeof(int) > ws_size && nblocks > 64)
        nblocks >>= 1;

    bincount_part<<<nblocks, 512, 0, stream>>>(x, n, part);
    bincount_reduce<<<NBINS, 64, 0, stream>>>(part, nblocks, out);
}